// Round 1
// baseline (602.227 us; speedup 1.0000x reference)
//
#include <hip/hip_runtime.h>

#define Bv 2
#define Tv 2048
#define Cv 2048
#define Hv 16
#define HKVv 4
#define HDv 128

typedef __attribute__((ext_vector_type(8))) __bf16 bf16x8;
typedef __attribute__((ext_vector_type(4))) float floatx4;

__device__ __forceinline__ unsigned short f2b(float f) {
  unsigned int x = __float_as_uint(f);
  x += 0x7fffu + ((x >> 16) & 1u);
  return (unsigned short)(x >> 16);
}

#define MFMA(a, b, c) __builtin_amdgcn_mfma_f32_16x16x32_bf16((a), (b), (c), 0, 0, 0)

// ---------------- fp32 -> bf16 contiguous cast ----------------
__global__ void cvt_kernel(const float* __restrict__ src, unsigned short* __restrict__ dst, int n4) {
  int i = blockIdx.x * blockDim.x + threadIdx.x;
  if (i < n4) {
    float4 f = ((const float4*)src)[i];
    ushort4 u;
    u.x = f2b(f.x); u.y = f2b(f.y); u.z = f2b(f.z); u.w = f2b(f.w);
    ((ushort4*)dst)[i] = u;
  }
}

// ---------------- transpose + cast: src (K x N) fp32 -> dst (N x K) bf16 ----------------
__global__ void tcvt_kernel(const float* __restrict__ src, unsigned short* __restrict__ dst, int K, int N) {
  __shared__ float tile[32][33];
  int k0 = blockIdx.x * 32, n0 = blockIdx.y * 32;
  int tx = threadIdx.x, ty = threadIdx.y;
  for (int i = ty; i < 32; i += 8)
    tile[i][tx] = src[(size_t)(k0 + i) * N + n0 + tx];
  __syncthreads();
  for (int i = ty; i < 32; i += 8)
    dst[(size_t)(n0 + i) * K + k0 + tx] = f2b(tile[tx][i]);
}

// ---------------- fused QKV GEMM: xb(4096x2048) @ [Wq | Wkv] -> q,k,v ----------------
// virtual N = 3072: [0,2048)=q cols, [2048,2560)=k cols, [2560,3072)=v cols
__global__ __launch_bounds__(256) void gemm_qkv(
    const unsigned short* __restrict__ xb,
    const unsigned short* __restrict__ wq_t,   // 2048 x 2048 (N-major)
    const unsigned short* __restrict__ wkv_t,  // 1024 x 2048 (N-major)
    const float* __restrict__ bq, const float* __restrict__ bkv,
    unsigned short* __restrict__ qs,   // (B,H,T,HD)
    unsigned short* __restrict__ ks,   // (B,HKV,T,HD)
    unsigned short* __restrict__ vs) { // (B,HKV,HD,T)  transposed
  __shared__ __align__(16) unsigned short Ash[128 * 32];
  __shared__ __align__(16) unsigned short Bsh[128 * 32];
  int tid = threadIdx.x;
  int wave = tid >> 6, lane = tid & 63;
  int c = lane & 15, quad = lane >> 4;
  int wr = (wave >> 1) * 64, wc = (wave & 1) * 64;
  int m0 = blockIdx.x * 128, n0 = blockIdx.y * 128;
  bool isq = (n0 < 2048);
  const unsigned short* wt = isq ? (wq_t + (size_t)n0 * 2048)
                                 : (wkv_t + (size_t)(n0 - 2048) * 2048);
  floatx4 zero4 = {0.f, 0.f, 0.f, 0.f};
  floatx4 acc[4][4];
#pragma unroll
  for (int i = 0; i < 4; i++)
#pragma unroll
    for (int j = 0; j < 4; j++) acc[i][j] = zero4;

  int arow = tid >> 2, acol = (tid & 3) * 8;
  const unsigned short* gA = xb + (size_t)(m0 + arow) * 2048 + acol;
  const unsigned short* gB = wt + (size_t)arow * 2048 + acol;

  for (int k0 = 0; k0 < 2048; k0 += 32) {
    *(int4*)(&Ash[tid * 8])        = *(const int4*)(gA + k0);
    *(int4*)(&Ash[2048 + tid * 8]) = *(const int4*)(gA + (size_t)64 * 2048 + k0);
    *(int4*)(&Bsh[tid * 8])        = *(const int4*)(gB + k0);
    *(int4*)(&Bsh[2048 + tid * 8]) = *(const int4*)(gB + (size_t)64 * 2048 + k0);
    __syncthreads();
    bf16x8 af[4], bfv[4];
#pragma unroll
    for (int i = 0; i < 4; i++)
      af[i] = *(const bf16x8*)(&Ash[(wr + i * 16 + c) * 32 + quad * 8]);
#pragma unroll
    for (int j = 0; j < 4; j++)
      bfv[j] = *(const bf16x8*)(&Bsh[(wc + j * 16 + c) * 32 + quad * 8]);
#pragma unroll
    for (int i = 0; i < 4; i++)
#pragma unroll
      for (int j = 0; j < 4; j++)
        acc[i][j] = MFMA(af[i], bfv[j], acc[i][j]);
    __syncthreads();
  }

#pragma unroll
  for (int i = 0; i < 4; i++) {
#pragma unroll
    for (int j = 0; j < 4; j++) {
#pragma unroll
      for (int r = 0; r < 4; r++) {
        int m = m0 + wr + i * 16 + quad * 4 + r;
        int n = n0 + wc + j * 16 + c;
        int bidx = m >> 11, t = m & 2047;
        float val = acc[i][j][r];
        if (isq) {
          val = (val + bq[n]) * 0.08838834764831845f;  // 1/sqrt(128)
          int hh = n >> 7, d = n & 127;
          qs[((size_t)((bidx * Hv + hh) * Tv) + t) * HDv + d] = f2b(val);
        } else {
          int n2 = n - 2048;
          val += bkv[n2];
          if (n2 < 512) {
            int hh = n2 >> 7, d = n2 & 127;
            ks[((size_t)((bidx * HKVv + hh) * Tv) + t) * HDv + d] = f2b(val);
          } else {
            int n3 = n2 - 512;
            int hh = n3 >> 7, d = n3 & 127;
            vs[((size_t)((bidx * HKVv + hh) * HDv) + d) * Tv + t] = f2b(val);
          }
        }
      }
    }
  }
}

// ---------------- causal flash attention ----------------
// grid (T/64, H, B); 256 threads = 4 waves; wave handles 16 q rows; BN=32 kv tile
__global__ __launch_bounds__(256) void attn_kernel(
    const unsigned short* __restrict__ qs,   // (B,H,T,HD), pre-scaled
    const unsigned short* __restrict__ ks,   // (B,HKV,T,HD)
    const unsigned short* __restrict__ vs,   // (B,HKV,HD,T)
    unsigned short* __restrict__ ys) {       // (B,T,C)
  __shared__ __align__(16) unsigned short Ksh[32 * 128];  // [kv][d]
  __shared__ __align__(16) unsigned short Vsh[128 * 32];  // [d][kv]
  __shared__ __align__(16) unsigned short Psh[4][16 * 32];

  int qt = blockIdx.x, h = blockIdx.y, b = blockIdx.z;
  int hkv = h & (HKVv - 1);
  int tid = threadIdx.x;
  int wave = tid >> 6, lane = tid & 63;
  int c = lane & 15, quad = lane >> 4;
  int q0w = qt * 64 + wave * 16;

  const unsigned short* qptr = qs + ((size_t)((b * Hv + h) * Tv) + q0w) * HDv;
  const unsigned short* kbase = ks + (size_t)((b * HKVv + hkv) * Tv) * HDv;
  const unsigned short* vbase = vs + (size_t)((b * HKVv + hkv) * HDv) * Tv;

  bf16x8 qf[4];
#pragma unroll
  for (int kc = 0; kc < 4; kc++)
    qf[kc] = *(const bf16x8*)(qptr + (size_t)c * HDv + kc * 32 + quad * 8);

  floatx4 o[8];
  floatx4 zero4 = {0.f, 0.f, 0.f, 0.f};
#pragma unroll
  for (int dt = 0; dt < 8; dt++) o[dt] = zero4;
  float M[4] = {-1e30f, -1e30f, -1e30f, -1e30f};
  float L[4] = {0.f, 0.f, 0.f, 0.f};

  int ntiles = qt * 2 + 2;
  int qrow_base = q0w + quad * 4;

  for (int kt = 0; kt < ntiles; kt++) {
    int kv0 = kt * 32;
    __syncthreads();  // previous tile's LDS reads complete
    {
      int ch0 = tid, ch1 = tid + 256;
      *(int4*)(&Ksh[ch0 * 8]) = *(const int4*)(kbase + (size_t)(kv0 + (ch0 >> 4)) * 128 + (ch0 & 15) * 8);
      *(int4*)(&Ksh[ch1 * 8]) = *(const int4*)(kbase + (size_t)(kv0 + (ch1 >> 4)) * 128 + (ch1 & 15) * 8);
      *(int4*)(&Vsh[ch0 * 8]) = *(const int4*)(vbase + (size_t)(ch0 >> 2) * Tv + kv0 + (ch0 & 3) * 8);
      *(int4*)(&Vsh[ch1 * 8]) = *(const int4*)(vbase + (size_t)(ch1 >> 2) * Tv + kv0 + (ch1 & 3) * 8);
    }
    __syncthreads();

    floatx4 s0 = zero4, s1 = zero4;
#pragma unroll
    for (int kc = 0; kc < 4; kc++) {
      bf16x8 k0f = *(const bf16x8*)(&Ksh[(size_t)c * 128 + kc * 32 + quad * 8]);
      bf16x8 k1f = *(const bf16x8*)(&Ksh[(size_t)(16 + c) * 128 + kc * 32 + quad * 8]);
      s0 = MFMA(qf[kc], k0f, s0);
      s1 = MFMA(qf[kc], k1f, s1);
    }

    float alr[4];
#pragma unroll
    for (int r = 0; r < 4; r++) {
      int qr = qrow_base + r;
      float v0 = (kv0 + c <= qr) ? s0[r] : -1e30f;
      float v1 = (kv0 + 16 + c <= qr) ? s1[r] : -1e30f;
      float m = fmaxf(v0, v1);
      m = fmaxf(m, __shfl_xor(m, 8));
      m = fmaxf(m, __shfl_xor(m, 4));
      m = fmaxf(m, __shfl_xor(m, 2));
      m = fmaxf(m, __shfl_xor(m, 1));
      float Mn = fmaxf(M[r], m);
      float al = __expf(M[r] - Mn);
      float p0 = __expf(v0 - Mn);
      float p1 = __expf(v1 - Mn);
      float l = p0 + p1;
      l += __shfl_xor(l, 8);
      l += __shfl_xor(l, 4);
      l += __shfl_xor(l, 2);
      l += __shfl_xor(l, 1);
      L[r] = L[r] * al + l;
      M[r] = Mn;
      alr[r] = al;
      Psh[wave][(quad * 4 + r) * 32 + c] = f2b(p0);
      Psh[wave][(quad * 4 + r) * 32 + 16 + c] = f2b(p1);
    }
#pragma unroll
    for (int dt = 0; dt < 8; dt++) {
      o[dt][0] *= alr[0]; o[dt][1] *= alr[1];
      o[dt][2] *= alr[2]; o[dt][3] *= alr[3];
    }
    __syncthreads();  // P visible (wave-local, but uniform barrier is safe+simple)

    bf16x8 pf = *(const bf16x8*)(&Psh[wave][c * 32 + quad * 8]);
#pragma unroll
    for (int dt = 0; dt < 8; dt++) {
      bf16x8 vf = *(const bf16x8*)(&Vsh[(dt * 16 + c) * 32 + quad * 8]);
      o[dt] = MFMA(pf, vf, o[dt]);
    }
  }

  float Li[4];
#pragma unroll
  for (int r = 0; r < 4; r++) Li[r] = 1.0f / L[r];
#pragma unroll
  for (int dt = 0; dt < 8; dt++) {
#pragma unroll
    for (int r = 0; r < 4; r++) {
      int t = q0w + quad * 4 + r;
      ys[((size_t)(b * Tv + t)) * Cv + h * HDv + dt * 16 + c] = f2b(o[dt][r] * Li[r]);
    }
  }
}

// ---------------- output projection: ys(4096x2048) @ Wp + bp -> out fp32 ----------------
__global__ __launch_bounds__(256) void gemm_proj(
    const unsigned short* __restrict__ ys,
    const unsigned short* __restrict__ wp_t,  // 2048 x 2048 (N-major)
    const float* __restrict__ bp,
    float* __restrict__ out) {
  __shared__ __align__(16) unsigned short Ash[128 * 32];
  __shared__ __align__(16) unsigned short Bsh[128 * 32];
  int tid = threadIdx.x;
  int wave = tid >> 6, lane = tid & 63;
  int c = lane & 15, quad = lane >> 4;
  int wr = (wave >> 1) * 64, wc = (wave & 1) * 64;
  int m0 = blockIdx.x * 128, n0 = blockIdx.y * 128;
  floatx4 zero4 = {0.f, 0.f, 0.f, 0.f};
  floatx4 acc[4][4];
#pragma unroll
  for (int i = 0; i < 4; i++)
#pragma unroll
    for (int j = 0; j < 4; j++) acc[i][j] = zero4;

  int arow = tid >> 2, acol = (tid & 3) * 8;
  const unsigned short* gA = ys + (size_t)(m0 + arow) * 2048 + acol;
  const unsigned short* gB = wp_t + (size_t)(n0 + arow) * 2048 + acol;

  for (int k0 = 0; k0 < 2048; k0 += 32) {
    *(int4*)(&Ash[tid * 8])        = *(const int4*)(gA + k0);
    *(int4*)(&Ash[2048 + tid * 8]) = *(const int4*)(gA + (size_t)64 * 2048 + k0);
    *(int4*)(&Bsh[tid * 8])        = *(const int4*)(gB + k0);
    *(int4*)(&Bsh[2048 + tid * 8]) = *(const int4*)(gB + (size_t)64 * 2048 + k0);
    __syncthreads();
    bf16x8 af[4], bfv[4];
#pragma unroll
    for (int i = 0; i < 4; i++)
      af[i] = *(const bf16x8*)(&Ash[(wr + i * 16 + c) * 32 + quad * 8]);
#pragma unroll
    for (int j = 0; j < 4; j++)
      bfv[j] = *(const bf16x8*)(&Bsh[(wc + j * 16 + c) * 32 + quad * 8]);
#pragma unroll
    for (int i = 0; i < 4; i++)
#pragma unroll
      for (int j = 0; j < 4; j++)
        acc[i][j] = MFMA(af[i], bfv[j], acc[i][j]);
    __syncthreads();
  }

#pragma unroll
  for (int i = 0; i < 4; i++) {
#pragma unroll
    for (int j = 0; j < 4; j++) {
#pragma unroll
      for (int r = 0; r < 4; r++) {
        int m = m0 + wr + i * 16 + quad * 4 + r;
        int n = n0 + wc + j * 16 + c;
        out[(size_t)m * 2048 + n] = acc[i][j][r] + bp[n];
      }
    }
  }
}

extern "C" void kernel_launch(void* const* d_in, const int* in_sizes, int n_in,
                              void* d_out, int out_size, void* d_ws, size_t ws_size,
                              hipStream_t stream) {
  (void)in_sizes; (void)n_in; (void)out_size; (void)ws_size;
  const float* x   = (const float*)d_in[0];
  const float* Wkv = (const float*)d_in[1];
  const float* bkv = (const float*)d_in[2];
  const float* Wq  = (const float*)d_in[3];
  const float* bq  = (const float*)d_in[4];
  const float* Wp  = (const float*)d_in[5];
  const float* bp  = (const float*)d_in[6];
  float* out = (float*)d_out;

  char* ws = (char*)d_ws;
  unsigned short* xb    = (unsigned short*)(ws + 0);          // 16.78 MB
  unsigned short* wq_t  = (unsigned short*)(ws + 16777216);   //  8.39 MB
  unsigned short* wkv_t = (unsigned short*)(ws + 25165824);   //  4.19 MB
  unsigned short* wp_t  = (unsigned short*)(ws + 29360128);   //  8.39 MB
  unsigned short* qs    = (unsigned short*)(ws + 37748736);   // 16.78 MB
  unsigned short* ks    = (unsigned short*)(ws + 54525952);   //  4.19 MB
  unsigned short* vs    = (unsigned short*)(ws + 58720256);   //  4.19 MB
  unsigned short* ysbuf = (unsigned short*)(ws + 62914560);   // 16.78 MB  (end 79.7 MB)

  // x -> bf16
  cvt_kernel<<<8192, 256, 0, stream>>>(x, xb, 2097152);
  // weights -> bf16, transposed to N x K
  tcvt_kernel<<<dim3(64, 64), dim3(32, 8), 0, stream>>>(Wq, wq_t, 2048, 2048);
  tcvt_kernel<<<dim3(64, 32), dim3(32, 8), 0, stream>>>(Wkv, wkv_t, 2048, 1024);
  tcvt_kernel<<<dim3(64, 64), dim3(32, 8), 0, stream>>>(Wp, wp_t, 2048, 2048);
  // QKV projection (virtual N = 3072)
  gemm_qkv<<<dim3(32, 24), 256, 0, stream>>>(xb, wq_t, wkv_t, bq, bkv, qs, ks, vs);
  // causal flash attention
  attn_kernel<<<dim3(32, 16, 2), 256, 0, stream>>>(qs, ks, vs, ysbuf);
  // output projection
  gemm_proj<<<dim3(32, 16), 256, 0, stream>>>(ysbuf, wp_t, bp, out);
}

// Round 2
// 401.697 us; speedup vs baseline: 1.4992x; 1.4992x over previous
//
#include <hip/hip_runtime.h>

#define Bv 2
#define Tv 2048
#define Cv 2048
#define Hv 16
#define HKVv 4
#define HDv 128

typedef __attribute__((ext_vector_type(8))) __bf16 bf16x8;
typedef __attribute__((ext_vector_type(4))) float floatx4;

__device__ __forceinline__ unsigned short f2b(float f) {
  unsigned int x = __float_as_uint(f);
  x += 0x7fffu + ((x >> 16) & 1u);
  return (unsigned short)(x >> 16);
}

#define MFMA(a, b, c) __builtin_amdgcn_mfma_f32_16x16x32_bf16((a), (b), (c), 0, 0, 0)

// async global->LDS, 16B per lane; dest = wave-uniform base + lane*16
__device__ __forceinline__ void gld_lds16(const void* g, void* l) {
  __builtin_amdgcn_global_load_lds((const __attribute__((address_space(1))) void*)g,
                                   (__attribute__((address_space(3))) void*)l, 16, 0, 0);
}

// ---------------- fp32 -> bf16 contiguous cast ----------------
__global__ void cvt_kernel(const float* __restrict__ src, unsigned short* __restrict__ dst, int n4) {
  int i = blockIdx.x * blockDim.x + threadIdx.x;
  if (i < n4) {
    float4 f = ((const float4*)src)[i];
    ushort4 u;
    u.x = f2b(f.x); u.y = f2b(f.y); u.z = f2b(f.z); u.w = f2b(f.w);
    ((ushort4*)dst)[i] = u;
  }
}

// ---------------- transpose + cast: src (K x N) fp32 -> dst (N x K) bf16 ----------------
__global__ void tcvt_kernel(const float* __restrict__ src, unsigned short* __restrict__ dst, int K, int N) {
  __shared__ float tile[32][33];
  int k0 = blockIdx.x * 32, n0 = blockIdx.y * 32;
  int tx = threadIdx.x, ty = threadIdx.y;
  for (int i = ty; i < 32; i += 8)
    tile[i][tx] = src[(size_t)(k0 + i) * N + n0 + tx];
  __syncthreads();
  for (int i = ty; i < 32; i += 8)
    dst[(size_t)(n0 + i) * K + k0 + tx] = f2b(tile[tx][i]);
}

// ---------------- fused QKV GEMM (m97-style staging + swizzled LDS) ----------------
__global__ __launch_bounds__(256) void gemm_qkv(
    const unsigned short* __restrict__ xb,
    const unsigned short* __restrict__ wq_t,   // 2048 x 2048 (N-major)
    const unsigned short* __restrict__ wkv_t,  // 1024 x 2048 (N-major)
    const float* __restrict__ bq, const float* __restrict__ bkv,
    unsigned short* __restrict__ qs,   // (B,H,T,HD)
    unsigned short* __restrict__ ks,   // (B,HKV,T,HD)
    unsigned short* __restrict__ vs) { // (B,HKV,HD,T)
  __shared__ __align__(16) unsigned short Ash[128 * 32];
  __shared__ __align__(16) unsigned short Bsh[128 * 32];
  int tid = threadIdx.x;
  int wave = tid >> 6, lane = tid & 63;
  int c = lane & 15, quad = lane >> 4;
  int wr = (wave >> 1) * 64, wc = (wave & 1) * 64;
  int m0 = blockIdx.x * 128, n0 = blockIdx.y * 128;
  bool isq = (n0 < 2048);
  const unsigned short* wt = isq ? (wq_t + (size_t)n0 * 2048)
                                 : (wkv_t + (size_t)(n0 - 2048) * 2048);
  floatx4 zero4 = {0.f, 0.f, 0.f, 0.f};
  floatx4 acc[4][4];
#pragma unroll
  for (int i = 0; i < 4; i++)
#pragma unroll
    for (int j = 0; j < 4; j++) acc[i][j] = zero4;

  const unsigned short* Abase = xb + (size_t)m0 * 2048;
  // per-wave staging lane mapping (slot = wave*128 + i*64 + lane)
  int s0 = wave * 128 + lane, s1 = wave * 128 + 64 + lane;
  int r0 = s0 >> 2, kc0 = (s0 & 3) ^ (r0 & 3);
  int r1 = s1 >> 2, kc1 = (s1 & 3) ^ (r1 & 3);
  int swz3 = quad ^ (c & 3);

  for (int k0 = 0; k0 < 2048; k0 += 32) {
    gld_lds16(Abase + (size_t)r0 * 2048 + k0 + kc0 * 8, Ash + (size_t)(wave * 128) * 8);
    gld_lds16(Abase + (size_t)r1 * 2048 + k0 + kc1 * 8, Ash + (size_t)(wave * 128 + 64) * 8);
    gld_lds16(wt + (size_t)r0 * 2048 + k0 + kc0 * 8, Bsh + (size_t)(wave * 128) * 8);
    gld_lds16(wt + (size_t)r1 * 2048 + k0 + kc1 * 8, Bsh + (size_t)(wave * 128 + 64) * 8);
    __syncthreads();
    bf16x8 af[4], bfv[4];
#pragma unroll
    for (int i = 0; i < 4; i++)
      af[i] = *(const bf16x8*)(&Ash[(wr + i * 16 + c) * 32 + swz3 * 8]);
#pragma unroll
    for (int j = 0; j < 4; j++)
      bfv[j] = *(const bf16x8*)(&Bsh[(wc + j * 16 + c) * 32 + swz3 * 8]);
#pragma unroll
    for (int i = 0; i < 4; i++)
#pragma unroll
      for (int j = 0; j < 4; j++)
        acc[i][j] = MFMA(af[i], bfv[j], acc[i][j]);
    __syncthreads();
  }

#pragma unroll
  for (int i = 0; i < 4; i++) {
#pragma unroll
    for (int j = 0; j < 4; j++) {
#pragma unroll
      for (int r = 0; r < 4; r++) {
        int m = m0 + wr + i * 16 + quad * 4 + r;
        int n = n0 + wc + j * 16 + c;
        int bidx = m >> 11, t = m & 2047;
        float val = acc[i][j][r];
        if (isq) {
          val = (val + bq[n]) * 0.08838834764831845f;  // 1/sqrt(128)
          int hh = n >> 7, d = n & 127;
          qs[((size_t)((bidx * Hv + hh) * Tv) + t) * HDv + d] = f2b(val);
        } else {
          int n2 = n - 2048;
          val += bkv[n2];
          if (n2 < 512) {
            int hh = n2 >> 7, d = n2 & 127;
            ks[((size_t)((bidx * HKVv + hh) * Tv) + t) * HDv + d] = f2b(val);
          } else {
            int n3 = n2 - 512;
            int hh = n3 >> 7, d = n3 & 127;
            vs[((size_t)((bidx * HKVv + hh) * HDv) + d) * Tv + t] = f2b(val);
          }
        }
      }
    }
  }
}

// ---------------- causal flash attention (S^T formulation) ----------------
// grid (T/64, H, B); 4 waves; wave = 16 q rows; BN=64 kv per tile
// S^T = K·Q^T so softmax dim lands in reg/quad axis: per-lane scalar M/L,
// 2 shuffles per tile, contiguous b64 P writes / b128 P reads.
__global__ __launch_bounds__(256, 4) void attn_kernel(
    const unsigned short* __restrict__ qs,   // (B,H,T,HD), pre-scaled
    const unsigned short* __restrict__ ks,   // (B,HKV,T,HD)
    const unsigned short* __restrict__ vs,   // (B,HKV,HD,T)
    unsigned short* __restrict__ ys) {       // (B,T,C) bf16
  __shared__ __align__(16) unsigned short Ksh[64 * 128];   // [kv][d], swizzled granules
  __shared__ __align__(16) unsigned short Vsh[128 * 64];   // [d][kv], swizzled granules
  __shared__ __align__(16) unsigned short Psh[4][16 * 64]; // per-wave [qrow][kv], swizzled

  int qt = blockIdx.x, h = blockIdx.y, b = blockIdx.z;
  int hkv = h & (HKVv - 1);
  int tid = threadIdx.x;
  int wave = tid >> 6, lane = tid & 63;
  int c = lane & 15, quad = lane >> 4;
  int q0w = qt * 64 + wave * 16;
  int qrow = q0w + c;
  int swz = c & 7;

  const unsigned short* qptr = qs + ((size_t)((b * Hv + h) * Tv) + q0w) * HDv;
  const unsigned short* kbase = ks + (size_t)((b * HKVv + hkv) * Tv) * HDv;
  const unsigned short* vbase = vs + (size_t)((b * HKVv + hkv) * HDv) * Tv;

  // Q fragment (B-operand): B[n=c][k=kc*32+quad*8+j]
  bf16x8 qf[4];
#pragma unroll
  for (int kc = 0; kc < 4; kc++)
    qf[kc] = *(const bf16x8*)(qptr + (size_t)c * HDv + kc * 32 + quad * 8);

  floatx4 zero4 = {0.f, 0.f, 0.f, 0.f};
  floatx4 o[8];
#pragma unroll
  for (int dt = 0; dt < 8; dt++) o[dt] = zero4;
  float M = -1e30f, L = 0.f;

  unsigned short* Pw = &Psh[wave][0];
  // staging lane mappings (16B granules). K: 1024 slots (64 rows x 16 g).
  // V: 1024 slots (128 rows x 8 g). slot = wave*256 + i*64 + lane.
  int ntiles = qt + 1;

  for (int kt = 0; kt < ntiles; kt++) {
    int kv0 = kt * 64;
#pragma unroll
    for (int i = 0; i < 4; i++) {
      int slot = wave * 256 + i * 64 + lane;
      int n = slot >> 4, g = (slot & 15) ^ (n & 7);
      gld_lds16(kbase + (size_t)(kv0 + n) * HDv + g * 8, Ksh + (size_t)(wave * 256 + i * 64) * 8);
    }
#pragma unroll
    for (int i = 0; i < 4; i++) {
      int slot = wave * 256 + i * 64 + lane;
      int n = slot >> 3, g = (slot & 7) ^ (n & 7);
      gld_lds16(vbase + (size_t)n * Tv + kv0 + g * 8, Vsh + (size_t)(wave * 256 + i * 64) * 8);
    }
    __syncthreads();   // drains vmcnt (global_load_lds) + all waves

    bool active = (kv0 <= q0w + 15);
    if (active) {
      // ---- S^T: A = K frag, B = Q frag; 4 jj tiles of 16 kv rows
      floatx4 st[4];
#pragma unroll
      for (int jj = 0; jj < 4; jj++) st[jj] = zero4;
#pragma unroll
      for (int kc = 0; kc < 4; kc++) {
#pragma unroll
        for (int jj = 0; jj < 4; jj++) {
          bf16x8 kf = *(const bf16x8*)(&Ksh[(jj * 16 + c) * 128 + (((kc * 4 + quad) ^ swz) * 8)]);
          st[jj] = MFMA(kf, qf[kc], st[jj]);
        }
      }
      // ---- causal mask (only diagonal tile)
      if (kv0 + 63 > q0w) {
#pragma unroll
        for (int jj = 0; jj < 4; jj++) {
          int kvb = kv0 + jj * 16 + quad * 4;
#pragma unroll
          for (int r = 0; r < 4; r++)
            if (kvb + r > qrow) st[jj][r] = -1e30f;
        }
      }
      // ---- online softmax (per-lane qrow = c; reduce over regs + quads)
      float mx = -1e30f;
#pragma unroll
      for (int jj = 0; jj < 4; jj++) {
        mx = fmaxf(mx, fmaxf(fmaxf(st[jj][0], st[jj][1]), fmaxf(st[jj][2], st[jj][3])));
      }
      mx = fmaxf(mx, __shfl_xor(mx, 16));
      mx = fmaxf(mx, __shfl_xor(mx, 32));
      float Mn = fmaxf(M, mx);
      float al = __expf(M - Mn);
      M = Mn;
      float l = 0.f;
#pragma unroll
      for (int jj = 0; jj < 4; jj++) {
        float p0 = __expf(st[jj][0] - Mn);
        float p1 = __expf(st[jj][1] - Mn);
        float p2 = __expf(st[jj][2] - Mn);
        float p3 = __expf(st[jj][3] - Mn);
        l += (p0 + p1) + (p2 + p3);
        unsigned int lo = (unsigned int)f2b(p0) | ((unsigned int)f2b(p1) << 16);
        unsigned int hi = (unsigned int)f2b(p2) | ((unsigned int)f2b(p3) << 16);
        int g = (jj * 2 + (quad >> 1)) ^ swz;
        *(uint2*)(&Pw[c * 64 + g * 8 + (quad & 1) * 4]) = make_uint2(lo, hi);
      }
      l += __shfl_xor(l, 16);
      l += __shfl_xor(l, 32);
      L = L * al + l;
#pragma unroll
      for (int dt = 0; dt < 8; dt++) o[dt] *= al;
      // ---- O^T += V^T · P^T  (A = V frag, B = P frag); wave-local P, no barrier
#pragma unroll
      for (int kc2 = 0; kc2 < 2; kc2++) {
        bf16x8 pf = *(const bf16x8*)(&Pw[c * 64 + (((kc2 * 4 + quad) ^ swz) * 8)]);
#pragma unroll
        for (int dt = 0; dt < 8; dt++) {
          bf16x8 vf = *(const bf16x8*)(&Vsh[(dt * 16 + c) * 64 + (((kc2 * 4 + quad) ^ swz) * 8)]);
          o[dt] = MFMA(vf, pf, o[dt]);
        }
      }
    }
    __syncthreads();   // all reads done before next tile's staging
  }

  // ---- epilogue: O^T C-layout -> ys[b][t=qrow][h*128 + d], packed 8B stores
  float Li = 1.0f / L;
  size_t rowbase = ((size_t)(b * Tv + qrow)) * Cv + h * HDv;
#pragma unroll
  for (int dt = 0; dt < 8; dt++) {
    unsigned int lo = (unsigned int)f2b(o[dt][0] * Li) | ((unsigned int)f2b(o[dt][1] * Li) << 16);
    unsigned int hi = (unsigned int)f2b(o[dt][2] * Li) | ((unsigned int)f2b(o[dt][3] * Li) << 16);
    *(uint2*)(&ys[rowbase + dt * 16 + quad * 4]) = make_uint2(lo, hi);
  }
}

// ---------------- output projection (m97-style staging + swizzled LDS) ----------------
__global__ __launch_bounds__(256) void gemm_proj(
    const unsigned short* __restrict__ ys,
    const unsigned short* __restrict__ wp_t,  // 2048 x 2048 (N-major)
    const float* __restrict__ bp,
    float* __restrict__ out) {
  __shared__ __align__(16) unsigned short Ash[128 * 32];
  __shared__ __align__(16) unsigned short Bsh[128 * 32];
  int tid = threadIdx.x;
  int wave = tid >> 6, lane = tid & 63;
  int c = lane & 15, quad = lane >> 4;
  int wr = (wave >> 1) * 64, wc = (wave & 1) * 64;
  int m0 = blockIdx.x * 128, n0 = blockIdx.y * 128;
  floatx4 zero4 = {0.f, 0.f, 0.f, 0.f};
  floatx4 acc[4][4];
#pragma unroll
  for (int i = 0; i < 4; i++)
#pragma unroll
    for (int j = 0; j < 4; j++) acc[i][j] = zero4;

  const unsigned short* Abase = ys + (size_t)m0 * 2048;
  const unsigned short* Bbase = wp_t + (size_t)n0 * 2048;
  int s0 = wave * 128 + lane, s1 = wave * 128 + 64 + lane;
  int r0 = s0 >> 2, kc0 = (s0 & 3) ^ (r0 & 3);
  int r1 = s1 >> 2, kc1 = (s1 & 3) ^ (r1 & 3);
  int swz3 = quad ^ (c & 3);

  for (int k0 = 0; k0 < 2048; k0 += 32) {
    gld_lds16(Abase + (size_t)r0 * 2048 + k0 + kc0 * 8, Ash + (size_t)(wave * 128) * 8);
    gld_lds16(Abase + (size_t)r1 * 2048 + k0 + kc1 * 8, Ash + (size_t)(wave * 128 + 64) * 8);
    gld_lds16(Bbase + (size_t)r0 * 2048 + k0 + kc0 * 8, Bsh + (size_t)(wave * 128) * 8);
    gld_lds16(Bbase + (size_t)r1 * 2048 + k0 + kc1 * 8, Bsh + (size_t)(wave * 128 + 64) * 8);
    __syncthreads();
    bf16x8 af[4], bfv[4];
#pragma unroll
    for (int i = 0; i < 4; i++)
      af[i] = *(const bf16x8*)(&Ash[(wr + i * 16 + c) * 32 + swz3 * 8]);
#pragma unroll
    for (int j = 0; j < 4; j++)
      bfv[j] = *(const bf16x8*)(&Bsh[(wc + j * 16 + c) * 32 + swz3 * 8]);
#pragma unroll
    for (int i = 0; i < 4; i++)
#pragma unroll
      for (int j = 0; j < 4; j++)
        acc[i][j] = MFMA(af[i], bfv[j], acc[i][j]);
    __syncthreads();
  }

#pragma unroll
  for (int i = 0; i < 4; i++) {
#pragma unroll
    for (int j = 0; j < 4; j++) {
#pragma unroll
      for (int r = 0; r < 4; r++) {
        int m = m0 + wr + i * 16 + quad * 4 + r;
        int n = n0 + wc + j * 16 + c;
        out[(size_t)m * 2048 + n] = acc[i][j][r] + bp[n];
      }
    }
  }
}

extern "C" void kernel_launch(void* const* d_in, const int* in_sizes, int n_in,
                              void* d_out, int out_size, void* d_ws, size_t ws_size,
                              hipStream_t stream) {
  (void)in_sizes; (void)n_in; (void)out_size; (void)ws_size;
  const float* x   = (const float*)d_in[0];
  const float* Wkv = (const float*)d_in[1];
  const float* bkv = (const float*)d_in[2];
  const float* Wq  = (const float*)d_in[3];
  const float* bq  = (const float*)d_in[4];
  const float* Wp  = (const float*)d_in[5];
  const float* bp  = (const float*)d_in[6];
  float* out = (float*)d_out;

  char* ws = (char*)d_ws;
  unsigned short* xb    = (unsigned short*)(ws + 0);          // 16.78 MB
  unsigned short* wq_t  = (unsigned short*)(ws + 16777216);   //  8.39 MB
  unsigned short* wkv_t = (unsigned short*)(ws + 25165824);   //  4.19 MB
  unsigned short* wp_t  = (unsigned short*)(ws + 29360128);   //  8.39 MB
  unsigned short* qs    = (unsigned short*)(ws + 37748736);   // 16.78 MB
  unsigned short* ks    = (unsigned short*)(ws + 54525952);   //  4.19 MB
  unsigned short* vs    = (unsigned short*)(ws + 58720256);   //  4.19 MB
  unsigned short* ysbuf = (unsigned short*)(ws + 62914560);   // 16.78 MB  (end 79.7 MB)

  cvt_kernel<<<8192, 256, 0, stream>>>(x, xb, 2097152);
  tcvt_kernel<<<dim3(64, 64), dim3(32, 8), 0, stream>>>(Wq, wq_t, 2048, 2048);
  tcvt_kernel<<<dim3(64, 32), dim3(32, 8), 0, stream>>>(Wkv, wkv_t, 2048, 1024);
  tcvt_kernel<<<dim3(64, 64), dim3(32, 8), 0, stream>>>(Wp, wp_t, 2048, 2048);
  gemm_qkv<<<dim3(32, 24), 256, 0, stream>>>(xb, wq_t, wkv_t, bq, bkv, qs, ks, vs);
  attn_kernel<<<dim3(32, 16, 2), 256, 0, stream>>>(qs, ks, vs, ysbuf);
  gemm_proj<<<dim3(32, 16), 256, 0, stream>>>(ysbuf, wp_t, bp, out);
}